// Round 20
// baseline (165.383 us; speedup 1.0000x reference)
//
#include <hip/hip_runtime.h>
#include <math.h>

#define NRES 4096
#define SS   128
#define A0C  5
#define ATOT 16
#define LD   256
#define PD   64
#define HD   128

typedef __attribute__((ext_vector_type(8))) short bf16x8;
typedef __attribute__((ext_vector_type(4))) float f32x4;
typedef __attribute__((ext_vector_type(4))) unsigned int u32x4;

__device__ __forceinline__ unsigned short f2bf(float x){
    unsigned int u = __builtin_bit_cast(unsigned int, x);
    unsigned int r = u + 0x7FFFu + ((u >> 16) & 1u);   // RNE to bf16
    return (unsigned short)(r >> 16);
}
__device__ __forceinline__ unsigned short f2bfhu(float x){
    return (unsigned short)((__builtin_bit_cast(unsigned int, x) + 0x8000u) >> 16);
}
__device__ __forceinline__ unsigned int pk2bf(float lo, float hi){
    unsigned int a = __builtin_bit_cast(unsigned int, lo) + 0x8000u;
    unsigned int b = __builtin_bit_cast(unsigned int, hi) + 0x8000u;
    return __builtin_amdgcn_perm(b, a, 0x07060302u);
}
__device__ __forceinline__ float gelu_f(float x){
    float e = __builtin_amdgcn_exp2f(-2.3022082f * x * (1.0f + 0.044715f * x * x));
    return x * __builtin_amdgcn_rcpf(1.0f + e);
}
__device__ __forceinline__ f32x4 MFMA(bf16x8 a, bf16x8 b, f32x4 c){
    return __builtin_amdgcn_mfma_f32_16x16x32_bf16(a, b, c, 0, 0, 0);
}
// widen 4 consecutive bf16 (8B-aligned) to f32x4
__device__ __forceinline__ f32x4 ld4bf(const unsigned short* p){
    unsigned int u01 = *(const unsigned int*)(p);
    unsigned int u23 = *(const unsigned int*)(p + 2);
    f32x4 r;
    r[0] = __builtin_bit_cast(float, u01 << 16);
    r[1] = __builtin_bit_cast(float, u01 & 0xFFFF0000u);
    r[2] = __builtin_bit_cast(float, u23 << 16);
    r[3] = __builtin_bit_cast(float, u23 & 0xFFFF0000u);
    return r;
}

// ---------------- prep: transpose+convert weights to bf16 in d_ws ----------------
// layout (ushort elements)  [identical to r5..r19 — 73728 B total]:
//   [0)      wsD   [64 n][256 k]   (w_dist^T)
//   [16384)  wsDir [64 n][64 k]    (w_dir^T, k>=48 zero)
//   [20480)  wsM1  [128 n][64 k]   (w_mlp1^T)
//   [28672)  wsM2  [64 n][128 k]   (w_mlp2^T)
__global__ void smol_prep(const float* __restrict__ wdist, const float* __restrict__ wdir,
                          const float* __restrict__ wm1,  const float* __restrict__ wm2,
                          unsigned short* __restrict__ ws)
{
    int i = blockIdx.x * 256 + threadIdx.x;
    if (i < 16384){
        int nn = i >> 8, k = i & 255;
        ws[i] = f2bf(wdist[k*64 + nn]);
    } else if (i < 20480){
        int j = i - 16384; int nn = j >> 6, k = j & 63;
        ws[i] = (k < 48) ? f2bf(wdir[k*64 + nn]) : (unsigned short)0;
    } else if (i < 28672){
        int j = i - 20480; int nn = j >> 6, k = j & 63;
        ws[i] = f2bf(wm1[k*128 + nn]);
    } else if (i < 36864){
        int j = i - 28672; int nn = j >> 7, k = j & 127;
        ws[i] = f2bf(wm2[k*64 + nn]);
    }
}

// ---------------- main fused kernel ----------------
// r20 = r19 schedule EXACTLY + LDS diet to <=32KB -> 5 blocks/CU:
//  - loc UNIONed with {red,fin} (disjoint lifetimes, barrier-separated)
//  - wtype stored as bf16 in LDS (widened at LN)
//  - typef LDS deleted (ty read from global into regs at start)
//  - mask stored as uchar
struct __align__(16) SMem {
    unsigned short wbuf[64*72];     // 9216 B staged weight slice
    union {
        float  dist[128*17];        // live until dir phase
        unsigned short hidT[128*72];// live in MLP1/MLP2 (after barrier)
    };
    union {
        float loc[LD];              // precompute phase only
        struct { float red[4*PD]; float fin[PD]; } rf;  // final phase only
    };
    float  posall3[ATOT*3];
    unsigned short wtypeh[7*PD];    // bf16 type embeddings
    float  basev[PD];
    float  lnsc[PD], lnof[PD];
    float  b1v[HD];
    float  b2v[PD];
    float  gatevv[PD];
    unsigned char maskb[SS];
    float  pl[33];
    float  rot[9];
    float  ca3[3];
    float  cnt;
};

__device__ __forceinline__ float dirv2(const SMem& sm, float px, float py, float pz,
                                       int sl, int k){
    int kc = (k < 48) ? k : 47;
    int a = (kc * 21846) >> 16;     // kc/3
    int c = kc - 3*a;
    float pc = (c == 0) ? px : ((c == 1) ? py : pz);
    float e = (pc - sm.posall3[a*3+c]) * __builtin_amdgcn_rcpf(sm.dist[sl*17 + a]);
    return (k < 48) ? e : 0.0f;
}

__device__ __forceinline__ void loadStage(const unsigned short* __restrict__ src, int stride,
                                          int tid, u32x4& a, u32x4& b){
    int r = tid >> 3, s = (tid & 7) * 8;
    a = *(const u32x4*)&src[r*stride + s];
    b = *(const u32x4*)&src[(r+32)*stride + s];
}
__device__ __forceinline__ void pubStage(u32x4 a, u32x4 b, unsigned short* dst, int tid){
    __syncthreads();
    int r = tid >> 3, s = (tid & 7) * 8;
    *(u32x4*)&dst[r*72 + s]      = a;
    *(u32x4*)&dst[(r+32)*72 + s] = b;
    __syncthreads();
}

// RBF feature fragment
#define RBF_FRAG(av, sl) do {                                               \
    float dA_ = sm.dist[(sl)*17 + 2*kk + (g>>1)] * 1.60149654f;             \
    float z0_ = dA_ - (b0c + 0.00000000f);                                  \
    float z1_ = dA_ - (b0c + 1.28119724f);                                  \
    float z2_ = dA_ - (b0c + 2.56239447f);                                  \
    float z3_ = dA_ - (b0c + 3.84359171f);                                  \
    float z4_ = dA_ - (b0c + 5.12478894f);                                  \
    float z5_ = dA_ - (b0c + 6.40598618f);                                  \
    float z6_ = dA_ - (b0c + 7.68718342f);                                  \
    float z7_ = dA_ - (b0c + 8.96838065f);                                  \
    unsigned int w0_ = pk2bf(__builtin_amdgcn_exp2f((-z0_)*z0_),            \
                             __builtin_amdgcn_exp2f((-z1_)*z1_));           \
    unsigned int w1_ = pk2bf(__builtin_amdgcn_exp2f((-z2_)*z2_),            \
                             __builtin_amdgcn_exp2f((-z3_)*z3_));           \
    unsigned int w2_ = pk2bf(__builtin_amdgcn_exp2f((-z4_)*z4_),            \
                             __builtin_amdgcn_exp2f((-z5_)*z5_));           \
    unsigned int w3_ = pk2bf(__builtin_amdgcn_exp2f((-z6_)*z6_),            \
                             __builtin_amdgcn_exp2f((-z7_)*z7_));           \
    av = __builtin_bit_cast(bf16x8, (u32x4){w0_, w1_, w2_, w3_});           \
} while(0)

// Assemble MLP1 A-frag from LN'd registers (r19 mapping, verified).
#define MK_FRAG(F, Lm0, Lm1) do {                                           \
    float a0_ = __shfl(Lm0[0], srcA), b0_ = __shfl(Lm1[0], srcA);           \
    float a1_ = __shfl(Lm0[1], srcA), b1_ = __shfl(Lm1[1], srcA);           \
    float a2_ = __shfl(Lm0[2], srcA), b2_ = __shfl(Lm1[2], srcA);           \
    float a3_ = __shfl(Lm0[3], srcA), b3_ = __shfl(Lm1[3], srcA);           \
    float a4_ = __shfl(Lm0[0], srcB), b4_ = __shfl(Lm1[0], srcB);           \
    float a5_ = __shfl(Lm0[1], srcB), b5_ = __shfl(Lm1[1], srcB);           \
    float a6_ = __shfl(Lm0[2], srcB), b6_ = __shfl(Lm1[2], srcB);           \
    float a7_ = __shfl(Lm0[3], srcB), b7_ = __shfl(Lm1[3], srcB);           \
    float v0_ = hi ? b0_ : a0_;  float v1_ = hi ? b1_ : a1_;                \
    float v2_ = hi ? b2_ : a2_;  float v3_ = hi ? b3_ : a3_;                \
    float v4_ = hi ? b4_ : a4_;  float v5_ = hi ? b5_ : a5_;                \
    float v6_ = hi ? b6_ : a6_;  float v7_ = hi ? b7_ : a7_;                \
    F = __builtin_bit_cast(bf16x8, (u32x4){pk2bf(v0_,v1_), pk2bf(v2_,v3_),  \
                                           pk2bf(v4_,v5_), pk2bf(v6_,v7_)});\
} while(0)

// LN epilogue for one s-tile (wtype widened from bf16 LDS).
#define TILE_LN(L0, L1, L2, L3, A0, A1, A2, A3, tyv) do {                   \
    f32x4 v0_ = A0 + bV0 + ld4bf(&sm.wtypeh[(tyv)*PD + pb +  0]);           \
    f32x4 v1_ = A1 + bV1 + ld4bf(&sm.wtypeh[(tyv)*PD + pb + 16]);           \
    f32x4 v2_ = A2 + bV2 + ld4bf(&sm.wtypeh[(tyv)*PD + pb + 32]);           \
    f32x4 v3_ = A3 + bV3 + ld4bf(&sm.wtypeh[(tyv)*PD + pb + 48]);           \
    float ss_ = v0_[0]+v0_[1]+v0_[2]+v0_[3] + v1_[0]+v1_[1]+v1_[2]+v1_[3]   \
              + v2_[0]+v2_[1]+v2_[2]+v2_[3] + v3_[0]+v3_[1]+v3_[2]+v3_[3];  \
    ss_ += __shfl_xor(ss_,16); ss_ += __shfl_xor(ss_,32);                   \
    float mu_ = ss_ * (1.0f/64.0f);                                         \
    f32x4 d0_ = v0_ - mu_, d1_ = v1_ - mu_, d2_ = v2_ - mu_, d3_ = v3_ - mu_;\
    float sq_ = d0_[0]*d0_[0]+d0_[1]*d0_[1]+d0_[2]*d0_[2]+d0_[3]*d0_[3]     \
              + d1_[0]*d1_[0]+d1_[1]*d1_[1]+d1_[2]*d1_[2]+d1_[3]*d1_[3]     \
              + d2_[0]*d2_[0]+d2_[1]*d2_[1]+d2_[2]*d2_[2]+d2_[3]*d2_[3]     \
              + d3_[0]*d3_[0]+d3_[1]*d3_[1]+d3_[2]*d3_[2]+d3_[3]*d3_[3];    \
    sq_ += __shfl_xor(sq_,16); sq_ += __shfl_xor(sq_,32);                   \
    float inv_ = __builtin_amdgcn_rsqf(sq_*(1.0f/64.0f) + 1e-5f);           \
    L0 = d0_*inv_*sV0 + oV0;  L1 = d1_*inv_*sV1 + oV1;                      \
    L2 = d2_*inv_*sV2 + oV2;  L3 = d3_*inv_*sV3 + oV3;                      \
} while(0)

__global__ __launch_bounds__(256, 5)
void smol_fused(const float* __restrict__ g_local,
                const float* __restrict__ g_pos,
                const int*   __restrict__ g_type,
                const float* __restrict__ g_spos,
                const int*   __restrict__ g_mask,
                const float* __restrict__ w_points,
                const float* __restrict__ w_local,
                const float* __restrict__ w_type,
                const float* __restrict__ ln_scale,
                const float* __restrict__ ln_offset,
                const float* __restrict__ b_mlp1,
                const float* __restrict__ b_mlp2,
                const float* __restrict__ w_gate,
                const float* __restrict__ w_out,
                const unsigned short* __restrict__ ws,
                float* __restrict__ g_out)
{
    __shared__ SMem sm;
    const int n    = blockIdx.x;
    const int tid  = threadIdx.x;
    const int wv   = tid >> 6;        // wave 0..3 : owns rows 32wv..32wv+31
    const int lane = tid & 63;
    const int cB   = lane & 15;
    const int g    = lane >> 4;       // k-subgroup 0..3
    const int sl0  = 32*wv + cB;      // tile-0 s row (lane-local)
    const int sl1  = sl0 + 16;        // tile-1 s row

    const unsigned short* wsD   = ws;
    const unsigned short* wsDir = ws + 16384;
    const unsigned short* wsM1  = ws + 20480;
    const unsigned short* wsM2  = ws + 28672;

    // per-lane type ids straight from global into registers (L2-hot)
    const int ty0 = g_type[n*SS + sl0];
    const int ty1 = g_type[n*SS + sl1];

    // ---------- stage per-n data + small weights ----------
    sm.loc[tid] = g_local[n*LD + tid];
    sm.wtypeh[tid] = f2bf(w_type[tid]);
    if (tid < 7*PD - 256) sm.wtypeh[256 + tid] = f2bf(w_type[256 + tid]);
    if (tid < PD){ sm.lnsc[tid] = ln_scale[tid]; sm.lnof[tid] = ln_offset[tid]; sm.b2v[tid] = b_mlp2[tid]; }
    if (tid < HD) sm.b1v[tid] = b_mlp1[tid];
    if (tid < SS) sm.maskb[tid] = (g_mask[n*SS + tid] != 0) ? 1 : 0;
    if (tid >= 128 && tid < 128 + A0C*3) sm.posall3[tid-128] = g_pos[n*A0C*3 + (tid-128)];
    __syncthreads();

    // ---------- per-n precompute ----------
    if (tid < 33){
        float a = 0.f;
        for (int i = 0; i < LD; ++i) a += sm.loc[i] * w_points[i*33 + tid];
        sm.pl[tid] = a;
    } else if (tid >= 64 && tid < 128){
        int p = tid - 64; float a = 0.f;
        for (int i = 0; i < LD; ++i) a += sm.loc[i] * w_local[i*PD + p];
        sm.basev[p] = a;
    } else if (tid >= 128 && tid < 192){
        int p = tid - 128; float a = 0.f;
        for (int i = 0; i < LD; ++i) a += sm.loc[i] * w_gate[i*PD + p];
        sm.gatevv[p] = gelu_f(a);
    } else if (tid == 255){
        float nx=sm.posall3[0], ny=sm.posall3[1], nz=sm.posall3[2];
        float cax=sm.posall3[3], cay=sm.posall3[4], caz=sm.posall3[5];
        float cx=sm.posall3[6], cy=sm.posall3[7], cz=sm.posall3[8];
        float v1x=cx-cax, v1y=cy-cay, v1z=cz-caz;
        float r = 1.0f/sqrtf(v1x*v1x + v1y*v1y + v1z*v1z + 1e-6f);
        float e1x=v1x*r, e1y=v1y*r, e1z=v1z*r;
        float v2x=nx-cax, v2y=ny-cay, v2z=nz-caz;
        float dp = e1x*v2x + e1y*v2y + e1z*v2z;
        float u2x=v2x-e1x*dp, u2y=v2y-e1y*dp, u2z=v2z-e1z*dp;
        r = 1.0f/sqrtf(u2x*u2x + u2y*u2y + u2z*u2z + 1e-6f);
        float e2x=u2x*r, e2y=u2y*r, e2z=u2z*r;
        float e3x=e1y*e2z-e1z*e2y, e3y=e1z*e2x-e1x*e2z, e3z=e1x*e2y-e1y*e2x;
        sm.rot[0]=e1x; sm.rot[1]=e2x; sm.rot[2]=e3x;
        sm.rot[3]=e1y; sm.rot[4]=e2y; sm.rot[5]=e3y;
        sm.rot[6]=e1z; sm.rot[7]=e2z; sm.rot[8]=e3z;
        sm.ca3[0]=cax; sm.ca3[1]=cay; sm.ca3[2]=caz;
    } else if (tid == 254){
        float c = 0.f;
        for (int s = 0; s < SS; ++s) c += (float)sm.maskb[s];
        sm.cnt = c;
    }
    __syncthreads();
    if (tid < 33){
        int k = tid / 3, i2 = tid - k*3;
        sm.posall3[(A0C + k)*3 + i2] =
            sm.rot[i2*3+0]*sm.pl[k*3+0] + sm.rot[i2*3+1]*sm.pl[k*3+1] +
            sm.rot[i2*3+2]*sm.pl[k*3+2] + sm.ca3[i2];
    }
    __syncthreads();   // posall3 visible to all waves

    // own-row smol coords in REGISTERS
    const float px0 = g_spos[(n*SS + sl0)*3 + 0];
    const float py0 = g_spos[(n*SS + sl0)*3 + 1];
    const float pz0 = g_spos[(n*SS + sl0)*3 + 2];
    const float px1 = g_spos[(n*SS + sl1)*3 + 0];
    const float py1 = g_spos[(n*SS + sl1)*3 + 1];
    const float pz1 = g_spos[(n*SS + sl1)*3 + 2];

    // prefetch slice 0 (wsD k 0..63)
    u32x4 pfa, pfb;
    loadStage(wsD, 256, tid, pfa, pfb);

    // dist for this wave's 32 rows
    #pragma unroll
    for (int aa = 0; aa < 4; ++aa){
        int a = g*4 + aa;
        float ax = sm.posall3[a*3+0], ay = sm.posall3[a*3+1], az = sm.posall3[a*3+2];
        float rx0 = px0-ax, ry0 = py0-ay, rz0 = pz0-az;
        sm.dist[sl0*17 + a] = sqrtf(rx0*rx0 + ry0*ry0 + rz0*rz0 + 1e-6f);
        float rx1 = px1-ax, ry1 = py1-ay, rz1 = pz1-az;
        sm.dist[sl1*17 + a] = sqrtf(rx1*rx1 + ry1*ry1 + rz1*rz1 + 1e-6f);
    }

    const float b0c = (float)((g&1) * 8) * 1.28119724f;
    const float b1a0 = sm.b1v[cB+0*16], b1a1 = sm.b1v[cB+1*16],
                b1a2 = sm.b1v[cB+2*16], b1a3 = sm.b1v[cB+3*16];
    const float b1b0 = sm.b1v[cB+4*16], b1b1 = sm.b1v[cB+5*16],
                b1b2 = sm.b1v[cB+6*16], b1b3 = sm.b1v[cB+7*16];

    // ---- pair GEMM (SWAPPED): accP_m = pair[p=16m+4g+r][s tile0], accQ_m tile1
    f32x4 accP0 = {0.f,0.f,0.f,0.f}, accP1 = accP0, accP2 = accP0, accP3 = accP0;
    f32x4 accQ0 = accP0, accQ1 = accP0, accQ2 = accP0, accQ3 = accP0;

    for (int h = 0; h < 4; ++h){
        pubStage(pfa, pfb, sm.wbuf, tid);
        if (h < 3) loadStage(wsD + (h+1)*64, 256, tid, pfa, pfb);
        else       loadStage(wsDir, 64, tid, pfa, pfb);
        #pragma unroll
        for (int kkl = 0; kkl < 2; ++kkl){
            const int kk = h*2 + kkl;
            bf16x8 av0, av1;
            RBF_FRAG(av0, sl0);
            RBF_FRAG(av1, sl1);
            const unsigned short* bb = &sm.wbuf[cB*72 + kkl*32 + g*8];
            bf16x8 B0 = *(const bf16x8*)(bb +  0*72);
            bf16x8 B1 = *(const bf16x8*)(bb + 16*72);
            bf16x8 B2 = *(const bf16x8*)(bb + 32*72);
            bf16x8 B3 = *(const bf16x8*)(bb + 48*72);
            accP0 = MFMA(B0, av0, accP0);  accQ0 = MFMA(B0, av1, accQ0);
            accP1 = MFMA(B1, av0, accP1);  accQ1 = MFMA(B1, av1, accQ1);
            accP2 = MFMA(B2, av0, accP2);  accQ2 = MFMA(B2, av1, accQ2);
            accP3 = MFMA(B3, av0, accP3);  accQ3 = MFMA(B3, av1, accQ3);
        }
    }

    // ---- + directions @ w_dir ----
    pubStage(pfa, pfb, sm.wbuf, tid);                 // wsDir
    loadStage(wsM1, 64, tid, pfa, pfb);               // prefetch M1a
    #pragma unroll
    for (int kk = 0; kk < 2; ++kk){
        int k0 = kk*32 + g*8;
        unsigned int a0w0 = pk2bf(dirv2(sm,px0,py0,pz0,sl0,k0+0), dirv2(sm,px0,py0,pz0,sl0,k0+1));
        unsigned int a0w1 = pk2bf(dirv2(sm,px0,py0,pz0,sl0,k0+2), dirv2(sm,px0,py0,pz0,sl0,k0+3));
        unsigned int a0w2 = pk2bf(dirv2(sm,px0,py0,pz0,sl0,k0+4), dirv2(sm,px0,py0,pz0,sl0,k0+5));
        unsigned int a0w3 = pk2bf(dirv2(sm,px0,py0,pz0,sl0,k0+6), dirv2(sm,px0,py0,pz0,sl0,k0+7));
        bf16x8 av0 = __builtin_bit_cast(bf16x8, (u32x4){a0w0,a0w1,a0w2,a0w3});
        unsigned int a1w0 = pk2bf(dirv2(sm,px1,py1,pz1,sl1,k0+0), dirv2(sm,px1,py1,pz1,sl1,k0+1));
        unsigned int a1w1 = pk2bf(dirv2(sm,px1,py1,pz1,sl1,k0+2), dirv2(sm,px1,py1,pz1,sl1,k0+3));
        unsigned int a1w2 = pk2bf(dirv2(sm,px1,py1,pz1,sl1,k0+4), dirv2(sm,px1,py1,pz1,sl1,k0+5));
        unsigned int a1w3 = pk2bf(dirv2(sm,px1,py1,pz1,sl1,k0+6), dirv2(sm,px1,py1,pz1,sl1,k0+7));
        bf16x8 av1 = __builtin_bit_cast(bf16x8, (u32x4){a1w0,a1w1,a1w2,a1w3});
        const unsigned short* bb = &sm.wbuf[cB*72 + k0];
        bf16x8 B0 = *(const bf16x8*)(bb +  0*72);
        bf16x8 B1 = *(const bf16x8*)(bb + 16*72);
        bf16x8 B2 = *(const bf16x8*)(bb + 32*72);
        bf16x8 B3 = *(const bf16x8*)(bb + 48*72);
        accP0 = MFMA(B0, av0, accP0);  accQ0 = MFMA(B0, av1, accQ0);
        accP1 = MFMA(B1, av0, accP1);  accQ1 = MFMA(B1, av1, accQ1);
        accP2 = MFMA(B2, av0, accP2);  accQ2 = MFMA(B2, av1, accQ2);
        accP3 = MFMA(B3, av0, accP3);  accQ3 = MFMA(B3, av1, accQ3);
    }

    // ---- epilogue: LN per s-row (lane-local), frags assembled in-register ----
    const int pb  = 4*g;
    const bool hi = (g >> 1);
    const int srcA = ((g&1) << 5) + cB;
    const int srcB = srcA + 16;

    const f32x4 bV0 = *(const f32x4*)&sm.basev[pb +  0];
    const f32x4 bV1 = *(const f32x4*)&sm.basev[pb + 16];
    const f32x4 bV2 = *(const f32x4*)&sm.basev[pb + 32];
    const f32x4 bV3 = *(const f32x4*)&sm.basev[pb + 48];
    const f32x4 sV0 = *(const f32x4*)&sm.lnsc[pb +  0];
    const f32x4 sV1 = *(const f32x4*)&sm.lnsc[pb + 16];
    const f32x4 sV2 = *(const f32x4*)&sm.lnsc[pb + 32];
    const f32x4 sV3 = *(const f32x4*)&sm.lnsc[pb + 48];
    const f32x4 oV0 = *(const f32x4*)&sm.lnof[pb +  0];
    const f32x4 oV1 = *(const f32x4*)&sm.lnof[pb + 16];
    const f32x4 oV2 = *(const f32x4*)&sm.lnof[pb + 32];
    const f32x4 oV3 = *(const f32x4*)&sm.lnof[pb + 48];

    bf16x8 F00, F01, F10, F11;
    {
        f32x4 L0, L1, L2, L3;
        TILE_LN(L0, L1, L2, L3, accP0, accP1, accP2, accP3, ty0);
        MK_FRAG(F00, L0, L1);
        MK_FRAG(F01, L2, L3);
    }
    {
        f32x4 L0, L1, L2, L3;
        TILE_LN(L0, L1, L2, L3, accQ0, accQ1, accQ2, accQ3, ty1);
        MK_FRAG(F10, L0, L1);
        MK_FRAG(F11, L2, L3);
    }

    // ==== MLP1/MLP2 interleaved in k-halves; A-frags from registers ====
    f32x4 accO0 = {0.f,0.f,0.f,0.f}, accO1 = accO0, accO2 = accO0, accO3 = accO0;
    f32x4 accN0 = accO0, accN1 = accO0, accN2 = accO0, accN3 = accO0;

    // ---- MLP1 half a ----
    f32x4 accH0 = {0.f,0.f,0.f,0.f}, accH1 = accH0, accH2 = accH0, accH3 = accH0;
    f32x4 accI0 = accH0, accI1 = accH0, accI2 = accH0, accI3 = accH0;
    pubStage(pfa, pfb, sm.wbuf, tid);                 // M1a; retires dist
    loadStage(wsM2, 128, tid, pfa, pfb);              // prefetch M2a
    #pragma unroll
    for (int kk = 0; kk < 2; ++kk){
        bf16x8 a0 = kk ? F01 : F00;
        bf16x8 a1 = kk ? F11 : F10;
        const unsigned short* bb = &sm.wbuf[cB*72 + kk*32 + g*8];
        bf16x8 B0 = *(const bf16x8*)(bb + 0*16*72);
        bf16x8 B1 = *(const bf16x8*)(bb + 1*16*72);
        bf16x8 B2 = *(const bf16x8*)(bb + 2*16*72);
        bf16x8 B3 = *(const bf16x8*)(bb + 3*16*72);
        accH0 = MFMA(a0, B0, accH0);  accI0 = MFMA(a1, B0, accI0);
        accH1 = MFMA(a0, B1, accH1);  accI1 = MFMA(a1, B1, accI1);
        accH2 = MFMA(a0, B2, accH2);  accI2 = MFMA(a1, B2, accI2);
        accH3 = MFMA(a0, B3, accH3);  accI3 = MFMA(a1, B3, accI3);
    }
    #pragma unroll
    for (int r = 0; r < 4; ++r){
        int slr0 = 32*wv + g*4 + r;
        unsigned short* hr0 = &sm.hidT[slr0*72];
        hr0[cB + 0*16] = f2bfhu(gelu_f(accH0[r] + b1a0));
        hr0[cB + 1*16] = f2bfhu(gelu_f(accH1[r] + b1a1));
        hr0[cB + 2*16] = f2bfhu(gelu_f(accH2[r] + b1a2));
        hr0[cB + 3*16] = f2bfhu(gelu_f(accH3[r] + b1a3));
        unsigned short* hr1 = &sm.hidT[(slr0+16)*72];
        hr1[cB + 0*16] = f2bfhu(gelu_f(accI0[r] + b1a0));
        hr1[cB + 1*16] = f2bfhu(gelu_f(accI1[r] + b1a1));
        hr1[cB + 2*16] = f2bfhu(gelu_f(accI2[r] + b1a2));
        hr1[cB + 3*16] = f2bfhu(gelu_f(accI3[r] + b1a3));
    }

    // ---- MLP2 k-half 0 ----
    pubStage(pfa, pfb, sm.wbuf, tid);                 // M2a; publishes hidT half a
    loadStage(wsM1 + 64*64, 64, tid, pfa, pfb);       // prefetch M1b
    #pragma unroll
    for (int kkl = 0; kkl < 2; ++kkl){
        bf16x8 a0 = *(const bf16x8*)&sm.hidT[sl0*72 + kkl*32 + g*8];
        bf16x8 a1 = *(const bf16x8*)&sm.hidT[sl1*72 + kkl*32 + g*8];
        const unsigned short* bb = &sm.wbuf[cB*72 + kkl*32 + g*8];
        bf16x8 B0 = *(const bf16x8*)(bb + 0*16*72);
        bf16x8 B1 = *(const bf16x8*)(bb + 1*16*72);
        bf16x8 B2 = *(const bf16x8*)(bb + 2*16*72);
        bf16x8 B3 = *(const bf16x8*)(bb + 3*16*72);
        accO0 = MFMA(a0, B0, accO0);  accN0 = MFMA(a1, B0, accN0);
        accO1 = MFMA(a0, B1, accO1);  accN1 = MFMA(a1, B1, accN1);
        accO2 = MFMA(a0, B2, accO2);  accN2 = MFMA(a1, B2, accN2);
        accO3 = MFMA(a0, B3, accO3);  accN3 = MFMA(a1, B3, accN3);
    }

    // ---- MLP1 half b (reusing the SAME frags) ----
    f32x4 accH4 = {0.f,0.f,0.f,0.f}, accH5 = accH4, accH6 = accH4, accH7 = accH4;
    f32x4 accI4 = accH4, accI5 = accH4, accI6 = accH4, accI7 = accH4;
    pubStage(pfa, pfb, sm.wbuf, tid);                 // M1b; retires hidT-half-a reads
    loadStage(wsM2 + 64, 128, tid, pfa, pfb);         // prefetch M2b
    #pragma unroll
    for (int kk = 0; kk < 2; ++kk){
        bf16x8 a0 = kk ? F01 : F00;
        bf16x8 a1 = kk ? F11 : F10;
        const unsigned short* bb = &sm.wbuf[cB*72 + kk*32 + g*8];
        bf16x8 B0 = *(const bf16x8*)(bb + 0*16*72);
        bf16x8 B1 = *(const bf16x8*)(bb + 1*16*72);
        bf16x8 B2 = *(const bf16x8*)(bb + 2*16*72);
        bf16x8 B3 = *(const bf16x8*)(bb + 3*16*72);
        accH4 = MFMA(a0, B0, accH4);  accI4 = MFMA(a1, B0, accI4);
        accH5 = MFMA(a0, B1, accH5);  accI5 = MFMA(a1, B1, accI5);
        accH6 = MFMA(a0, B2, accH6);  accI6 = MFMA(a1, B2, accI6);
        accH7 = MFMA(a0, B3, accH7);  accI7 = MFMA(a1, B3, accI7);
    }
    #pragma unroll
    for (int r = 0; r < 4; ++r){
        int slr0 = 32*wv + g*4 + r;
        unsigned short* hr0 = &sm.hidT[slr0*72];
        hr0[cB + 0*16] = f2bfhu(gelu_f(accH4[r] + b1b0));
        hr0[cB + 1*16] = f2bfhu(gelu_f(accH5[r] + b1b1));
        hr0[cB + 2*16] = f2bfhu(gelu_f(accH6[r] + b1b2));
        hr0[cB + 3*16] = f2bfhu(gelu_f(accH7[r] + b1b3));
        unsigned short* hr1 = &sm.hidT[(slr0+16)*72];
        hr1[cB + 0*16] = f2bfhu(gelu_f(accI4[r] + b1b0));
        hr1[cB + 1*16] = f2bfhu(gelu_f(accI5[r] + b1b1));
        hr1[cB + 2*16] = f2bfhu(gelu_f(accI6[r] + b1b2));
        hr1[cB + 3*16] = f2bfhu(gelu_f(accI7[r] + b1b3));
    }

    // ---- MLP2 k-half 1 ----
    pubStage(pfa, pfb, sm.wbuf, tid);                 // M2b; publishes hidT half b
    #pragma unroll
    for (int kkl = 0; kkl < 2; ++kkl){
        bf16x8 a0 = *(const bf16x8*)&sm.hidT[sl0*72 + kkl*32 + g*8];
        bf16x8 a1 = *(const bf16x8*)&sm.hidT[sl1*72 + kkl*32 + g*8];
        const unsigned short* bb = &sm.wbuf[cB*72 + kkl*32 + g*8];
        bf16x8 B0 = *(const bf16x8*)(bb + 0*16*72);
        bf16x8 B1 = *(const bf16x8*)(bb + 1*16*72);
        bf16x8 B2 = *(const bf16x8*)(bb + 2*16*72);
        bf16x8 B3 = *(const bf16x8*)(bb + 3*16*72);
        accO0 = MFMA(a0, B0, accO0);  accN0 = MFMA(a1, B0, accN0);
        accO1 = MFMA(a0, B1, accO1);  accN1 = MFMA(a1, B1, accN1);
        accO2 = MFMA(a0, B2, accO2);  accN2 = MFMA(a1, B2, accN2);
        accO3 = MFMA(a0, B3, accO3);  accN3 = MFMA(a1, B3, accN3);
    }

    float pooled0 = 0.f, pooled1 = 0.f, pooled2 = 0.f, pooled3 = 0.f;
    #pragma unroll
    for (int r = 0; r < 4; ++r){
        float m0f = sm.maskb[32*wv + g*4 + r]      ? 1.0f : 0.0f;
        float m1f = sm.maskb[32*wv + 16 + g*4 + r] ? 1.0f : 0.0f;
        pooled0 += m0f * accO0[r] + m1f * accN0[r];
        pooled1 += m0f * accO1[r] + m1f * accN1[r];
        pooled2 += m0f * accO2[r] + m1f * accN2[r];
        pooled3 += m0f * accO3[r] + m1f * accN3[r];
    }

    // ---- reduce pooled: across g-groups, then across waves ----
    pooled0 += __shfl_xor(pooled0,16); pooled0 += __shfl_xor(pooled0,32);
    pooled1 += __shfl_xor(pooled1,16); pooled1 += __shfl_xor(pooled1,32);
    pooled2 += __shfl_xor(pooled2,16); pooled2 += __shfl_xor(pooled2,32);
    pooled3 += __shfl_xor(pooled3,16); pooled3 += __shfl_xor(pooled3,32);
    if (g == 0){
        sm.rf.red[wv*PD + cB +  0] = pooled0;
        sm.rf.red[wv*PD + cB + 16] = pooled1;
        sm.rf.red[wv*PD + cB + 32] = pooled2;
        sm.rf.red[wv*PD + cB + 48] = pooled3;
    }
    __syncthreads();
    if (tid < PD){
        float v = sm.rf.red[tid] + sm.rf.red[PD + tid] + sm.rf.red[2*PD + tid] + sm.rf.red[3*PD + tid];
        float mc = fmaxf(sm.cnt, 1.0f);
        v = (v + sm.cnt * sm.b2v[tid]) / mc;
        sm.rf.fin[tid] = sm.gatevv[tid] * v;
    }
    __syncthreads();
    {
        float a = 0.f;
        #pragma unroll 4
        for (int p = 0; p < PD; ++p) a += sm.rf.fin[p] * w_out[p*LD + tid];
        g_out[n*LD + tid] = a;
    }
}

extern "C" void kernel_launch(void* const* d_in, const int* in_sizes, int n_in,
                              void* d_out, int out_size, void* d_ws, size_t ws_size,
                              hipStream_t stream)
{
    (void)in_sizes; (void)n_in; (void)out_size; (void)ws_size;
    const float* g_local   = (const float*)d_in[0];
    const float* g_pos     = (const float*)d_in[1];
    const int*   g_type    = (const int*)  d_in[2];
    const float* g_spos    = (const float*)d_in[3];
    const int*   g_mask    = (const int*)  d_in[4];
    const float* w_points  = (const float*)d_in[5];
    const float* w_type    = (const float*)d_in[6];
    const float* w_local   = (const float*)d_in[7];
    const float* w_dir     = (const float*)d_in[8];
    const float* w_dist    = (const float*)d_in[9];
    const float* ln_scale  = (const float*)d_in[10];
    const float* ln_offset = (const float*)d_in[11];
    const float* w_mlp1    = (const float*)d_in[12];
    const float* b_mlp1    = (const float*)d_in[13];
    const float* w_mlp2    = (const float*)d_in[14];
    const float* b_mlp2    = (const float*)d_in[15];
    const float* w_gate    = (const float*)d_in[16];
    const float* w_out     = (const float*)d_in[17];

    unsigned short* ws = (unsigned short*)d_ws;   // 73728 B

    smol_prep<<<dim3(144), dim3(256), 0, stream>>>(w_dist, w_dir, w_mlp1, w_mlp2, ws);

    smol_fused<<<dim3(NRES), dim3(256), 0, stream>>>(
        g_local, g_pos, g_type, g_spos, g_mask,
        w_points, w_local, w_type, ln_scale, ln_offset,
        b_mlp1, b_mlp2, w_gate, w_out, ws, (float*)d_out);
}

// Round 21
// 119.507 us; speedup vs baseline: 1.3839x; 1.3839x over previous
//
#include <hip/hip_runtime.h>
#include <math.h>

#define NRES 4096
#define SS   128
#define A0C  5
#define ATOT 16
#define LD   256
#define PD   64
#define HD   128

typedef __attribute__((ext_vector_type(8))) short bf16x8;
typedef __attribute__((ext_vector_type(4))) float f32x4;
typedef __attribute__((ext_vector_type(4))) unsigned int u32x4;

__device__ __forceinline__ unsigned short f2bf(float x){
    unsigned int u = __builtin_bit_cast(unsigned int, x);
    unsigned int r = u + 0x7FFFu + ((u >> 16) & 1u);   // RNE to bf16
    return (unsigned short)(r >> 16);
}
__device__ __forceinline__ unsigned short f2bfhu(float x){
    return (unsigned short)((__builtin_bit_cast(unsigned int, x) + 0x8000u) >> 16);
}
__device__ __forceinline__ unsigned int pk2bf(float lo, float hi){
    unsigned int a = __builtin_bit_cast(unsigned int, lo) + 0x8000u;
    unsigned int b = __builtin_bit_cast(unsigned int, hi) + 0x8000u;
    return __builtin_amdgcn_perm(b, a, 0x07060302u);
}
__device__ __forceinline__ float gelu_f(float x){
    float e = __builtin_amdgcn_exp2f(-2.3022082f * x * (1.0f + 0.044715f * x * x));
    return x * __builtin_amdgcn_rcpf(1.0f + e);
}
__device__ __forceinline__ f32x4 MFMA(bf16x8 a, bf16x8 b, f32x4 c){
    return __builtin_amdgcn_mfma_f32_16x16x32_bf16(a, b, c, 0, 0, 0);
}
// widen 4 consecutive bf16 (8B-aligned) to f32x4
__device__ __forceinline__ f32x4 ld4bf(const unsigned short* p){
    unsigned int u01 = *(const unsigned int*)(p);
    unsigned int u23 = *(const unsigned int*)(p + 2);
    f32x4 r;
    r[0] = __builtin_bit_cast(float, u01 << 16);
    r[1] = __builtin_bit_cast(float, u01 & 0xFFFF0000u);
    r[2] = __builtin_bit_cast(float, u23 << 16);
    r[3] = __builtin_bit_cast(float, u23 & 0xFFFF0000u);
    return r;
}

// ---------------- prep: transpose+convert weights to bf16 in d_ws ----------------
// layout (ushort elements)  [identical to r5..r20 — 73728 B total]:
//   [0)      wsD   [64 n][256 k]   (w_dist^T)
//   [16384)  wsDir [64 n][64 k]    (w_dir^T, k>=48 zero)
//   [20480)  wsM1  [128 n][64 k]   (w_mlp1^T)
//   [28672)  wsM2  [64 n][128 k]   (w_mlp2^T)
__global__ void smol_prep(const float* __restrict__ wdist, const float* __restrict__ wdir,
                          const float* __restrict__ wm1,  const float* __restrict__ wm2,
                          unsigned short* __restrict__ ws)
{
    int i = blockIdx.x * 256 + threadIdx.x;
    if (i < 16384){
        int nn = i >> 8, k = i & 255;
        ws[i] = f2bf(wdist[k*64 + nn]);
    } else if (i < 20480){
        int j = i - 16384; int nn = j >> 6, k = j & 63;
        ws[i] = (k < 48) ? f2bf(wdir[k*64 + nn]) : (unsigned short)0;
    } else if (i < 28672){
        int j = i - 20480; int nn = j >> 6, k = j & 63;
        ws[i] = f2bf(wm1[k*128 + nn]);
    } else if (i < 36864){
        int j = i - 28672; int nn = j >> 7, k = j & 127;
        ws[i] = f2bf(wm2[k*64 + nn]);
    }
}

// ---------------- main fused kernel ----------------
// r21 = r20's LDS diet (32256 B) + launch_bounds REVERTED to (256,4).
// r20's (256,5) capped VGPR at 48 -> scratch spills (WRITE 198MB). With
// (256,4) the allocator targets ~64 VGPR (r19 landed exactly 64); if it
// stays <=64, the HARDWARE can still co-schedule 5 blocks/CU because
// LDS (5x32256=161280 <= 163840) and VGPR (8 waves/SIMD at 64) both allow it.
struct __align__(16) SMem {
    unsigned short wbuf[64*72];     // 9216 B staged weight slice
    union {
        float  dist[128*17];        // live until dir phase
        unsigned short hidT[128*72];// live in MLP1/MLP2 (after barrier)
    };
    union {
        float loc[LD];              // precompute phase only
        struct { float red[4*PD]; float fin[PD]; } rf;  // final phase only
    };
    float  posall3[ATOT*3];
    unsigned short wtypeh[7*PD];    // bf16 type embeddings
    float  basev[PD];
    float  lnsc[PD], lnof[PD];
    float  b1v[HD];
    float  b2v[PD];
    float  gatevv[PD];
    unsigned char maskb[SS];
    float  pl[33];
    float  rot[9];
    float  ca3[3];
    float  cnt;
};

__device__ __forceinline__ float dirv2(const SMem& sm, float px, float py, float pz,
                                       int sl, int k){
    int kc = (k < 48) ? k : 47;
    int a = (kc * 21846) >> 16;     // kc/3
    int c = kc - 3*a;
    float pc = (c == 0) ? px : ((c == 1) ? py : pz);
    float e = (pc - sm.posall3[a*3+c]) * __builtin_amdgcn_rcpf(sm.dist[sl*17 + a]);
    return (k < 48) ? e : 0.0f;
}

__device__ __forceinline__ void loadStage(const unsigned short* __restrict__ src, int stride,
                                          int tid, u32x4& a, u32x4& b){
    int r = tid >> 3, s = (tid & 7) * 8;
    a = *(const u32x4*)&src[r*stride + s];
    b = *(const u32x4*)&src[(r+32)*stride + s];
}
__device__ __forceinline__ void pubStage(u32x4 a, u32x4 b, unsigned short* dst, int tid){
    __syncthreads();
    int r = tid >> 3, s = (tid & 7) * 8;
    *(u32x4*)&dst[r*72 + s]      = a;
    *(u32x4*)&dst[(r+32)*72 + s] = b;
    __syncthreads();
}

// RBF feature fragment
#define RBF_FRAG(av, sl) do {                                               \
    float dA_ = sm.dist[(sl)*17 + 2*kk + (g>>1)] * 1.60149654f;             \
    float z0_ = dA_ - (b0c + 0.00000000f);                                  \
    float z1_ = dA_ - (b0c + 1.28119724f);                                  \
    float z2_ = dA_ - (b0c + 2.56239447f);                                  \
    float z3_ = dA_ - (b0c + 3.84359171f);                                  \
    float z4_ = dA_ - (b0c + 5.12478894f);                                  \
    float z5_ = dA_ - (b0c + 6.40598618f);                                  \
    float z6_ = dA_ - (b0c + 7.68718342f);                                  \
    float z7_ = dA_ - (b0c + 8.96838065f);                                  \
    unsigned int w0_ = pk2bf(__builtin_amdgcn_exp2f((-z0_)*z0_),            \
                             __builtin_amdgcn_exp2f((-z1_)*z1_));           \
    unsigned int w1_ = pk2bf(__builtin_amdgcn_exp2f((-z2_)*z2_),            \
                             __builtin_amdgcn_exp2f((-z3_)*z3_));           \
    unsigned int w2_ = pk2bf(__builtin_amdgcn_exp2f((-z4_)*z4_),            \
                             __builtin_amdgcn_exp2f((-z5_)*z5_));           \
    unsigned int w3_ = pk2bf(__builtin_amdgcn_exp2f((-z6_)*z6_),            \
                             __builtin_amdgcn_exp2f((-z7_)*z7_));           \
    av = __builtin_bit_cast(bf16x8, (u32x4){w0_, w1_, w2_, w3_});           \
} while(0)

// Assemble MLP1 A-frag from LN'd registers (r19 mapping, verified).
#define MK_FRAG(F, Lm0, Lm1) do {                                           \
    float a0_ = __shfl(Lm0[0], srcA), b0_ = __shfl(Lm1[0], srcA);           \
    float a1_ = __shfl(Lm0[1], srcA), b1_ = __shfl(Lm1[1], srcA);           \
    float a2_ = __shfl(Lm0[2], srcA), b2_ = __shfl(Lm1[2], srcA);           \
    float a3_ = __shfl(Lm0[3], srcA), b3_ = __shfl(Lm1[3], srcA);           \
    float a4_ = __shfl(Lm0[0], srcB), b4_ = __shfl(Lm1[0], srcB);           \
    float a5_ = __shfl(Lm0[1], srcB), b5_ = __shfl(Lm1[1], srcB);           \
    float a6_ = __shfl(Lm0[2], srcB), b6_ = __shfl(Lm1[2], srcB);           \
    float a7_ = __shfl(Lm0[3], srcB), b7_ = __shfl(Lm1[3], srcB);           \
    float v0_ = hi ? b0_ : a0_;  float v1_ = hi ? b1_ : a1_;                \
    float v2_ = hi ? b2_ : a2_;  float v3_ = hi ? b3_ : a3_;                \
    float v4_ = hi ? b4_ : a4_;  float v5_ = hi ? b5_ : a5_;                \
    float v6_ = hi ? b6_ : a6_;  float v7_ = hi ? b7_ : a7_;                \
    F = __builtin_bit_cast(bf16x8, (u32x4){pk2bf(v0_,v1_), pk2bf(v2_,v3_),  \
                                           pk2bf(v4_,v5_), pk2bf(v6_,v7_)});\
} while(0)

// LN epilogue for one s-tile (wtype widened from bf16 LDS).
#define TILE_LN(L0, L1, L2, L3, A0, A1, A2, A3, tyv) do {                   \
    f32x4 v0_ = A0 + bV0 + ld4bf(&sm.wtypeh[(tyv)*PD + pb +  0]);           \
    f32x4 v1_ = A1 + bV1 + ld4bf(&sm.wtypeh[(tyv)*PD + pb + 16]);           \
    f32x4 v2_ = A2 + bV2 + ld4bf(&sm.wtypeh[(tyv)*PD + pb + 32]);           \
    f32x4 v3_ = A3 + bV3 + ld4bf(&sm.wtypeh[(tyv)*PD + pb + 48]);           \
    float ss_ = v0_[0]+v0_[1]+v0_[2]+v0_[3] + v1_[0]+v1_[1]+v1_[2]+v1_[3]   \
              + v2_[0]+v2_[1]+v2_[2]+v2_[3] + v3_[0]+v3_[1]+v3_[2]+v3_[3];  \
    ss_ += __shfl_xor(ss_,16); ss_ += __shfl_xor(ss_,32);                   \
    float mu_ = ss_ * (1.0f/64.0f);                                         \
    f32x4 d0_ = v0_ - mu_, d1_ = v1_ - mu_, d2_ = v2_ - mu_, d3_ = v3_ - mu_;\
    float sq_ = d0_[0]*d0_[0]+d0_[1]*d0_[1]+d0_[2]*d0_[2]+d0_[3]*d0_[3]     \
              + d1_[0]*d1_[0]+d1_[1]*d1_[1]+d1_[2]*d1_[2]+d1_[3]*d1_[3]     \
              + d2_[0]*d2_[0]+d2_[1]*d2_[1]+d2_[2]*d2_[2]+d2_[3]*d2_[3]     \
              + d3_[0]*d3_[0]+d3_[1]*d3_[1]+d3_[2]*d3_[2]+d3_[3]*d3_[3];    \
    sq_ += __shfl_xor(sq_,16); sq_ += __shfl_xor(sq_,32);                   \
    float inv_ = __builtin_amdgcn_rsqf(sq_*(1.0f/64.0f) + 1e-5f);           \
    L0 = d0_*inv_*sV0 + oV0;  L1 = d1_*inv_*sV1 + oV1;                      \
    L2 = d2_*inv_*sV2 + oV2;  L3 = d3_*inv_*sV3 + oV3;                      \
} while(0)

__global__ __launch_bounds__(256, 4)
void smol_fused(const float* __restrict__ g_local,
                const float* __restrict__ g_pos,
                const int*   __restrict__ g_type,
                const float* __restrict__ g_spos,
                const int*   __restrict__ g_mask,
                const float* __restrict__ w_points,
                const float* __restrict__ w_local,
                const float* __restrict__ w_type,
                const float* __restrict__ ln_scale,
                const float* __restrict__ ln_offset,
                const float* __restrict__ b_mlp1,
                const float* __restrict__ b_mlp2,
                const float* __restrict__ w_gate,
                const float* __restrict__ w_out,
                const unsigned short* __restrict__ ws,
                float* __restrict__ g_out)
{
    __shared__ SMem sm;
    const int n    = blockIdx.x;
    const int tid  = threadIdx.x;
    const int wv   = tid >> 6;        // wave 0..3 : owns rows 32wv..32wv+31
    const int lane = tid & 63;
    const int cB   = lane & 15;
    const int g    = lane >> 4;       // k-subgroup 0..3
    const int sl0  = 32*wv + cB;      // tile-0 s row (lane-local)
    const int sl1  = sl0 + 16;        // tile-1 s row

    const unsigned short* wsD   = ws;
    const unsigned short* wsDir = ws + 16384;
    const unsigned short* wsM1  = ws + 20480;
    const unsigned short* wsM2  = ws + 28672;

    // per-lane type ids straight from global into registers (L2-hot)
    const int ty0 = g_type[n*SS + sl0];
    const int ty1 = g_type[n*SS + sl1];

    // ---------- stage per-n data + small weights ----------
    sm.loc[tid] = g_local[n*LD + tid];
    sm.wtypeh[tid] = f2bf(w_type[tid]);
    if (tid < 7*PD - 256) sm.wtypeh[256 + tid] = f2bf(w_type[256 + tid]);
    if (tid < PD){ sm.lnsc[tid] = ln_scale[tid]; sm.lnof[tid] = ln_offset[tid]; sm.b2v[tid] = b_mlp2[tid]; }
    if (tid < HD) sm.b1v[tid] = b_mlp1[tid];
    if (tid < SS) sm.maskb[tid] = (g_mask[n*SS + tid] != 0) ? 1 : 0;
    if (tid >= 128 && tid < 128 + A0C*3) sm.posall3[tid-128] = g_pos[n*A0C*3 + (tid-128)];
    __syncthreads();

    // ---------- per-n precompute ----------
    if (tid < 33){
        float a = 0.f;
        for (int i = 0; i < LD; ++i) a += sm.loc[i] * w_points[i*33 + tid];
        sm.pl[tid] = a;
    } else if (tid >= 64 && tid < 128){
        int p = tid - 64; float a = 0.f;
        for (int i = 0; i < LD; ++i) a += sm.loc[i] * w_local[i*PD + p];
        sm.basev[p] = a;
    } else if (tid >= 128 && tid < 192){
        int p = tid - 128; float a = 0.f;
        for (int i = 0; i < LD; ++i) a += sm.loc[i] * w_gate[i*PD + p];
        sm.gatevv[p] = gelu_f(a);
    } else if (tid == 255){
        float nx=sm.posall3[0], ny=sm.posall3[1], nz=sm.posall3[2];
        float cax=sm.posall3[3], cay=sm.posall3[4], caz=sm.posall3[5];
        float cx=sm.posall3[6], cy=sm.posall3[7], cz=sm.posall3[8];
        float v1x=cx-cax, v1y=cy-cay, v1z=cz-caz;
        float r = 1.0f/sqrtf(v1x*v1x + v1y*v1y + v1z*v1z + 1e-6f);
        float e1x=v1x*r, e1y=v1y*r, e1z=v1z*r;
        float v2x=nx-cax, v2y=ny-cay, v2z=nz-caz;
        float dp = e1x*v2x + e1y*v2y + e1z*v2z;
        float u2x=v2x-e1x*dp, u2y=v2y-e1y*dp, u2z=v2z-e1z*dp;
        r = 1.0f/sqrtf(u2x*u2x + u2y*u2y + u2z*u2z + 1e-6f);
        float e2x=u2x*r, e2y=u2y*r, e2z=u2z*r;
        float e3x=e1y*e2z-e1z*e2y, e3y=e1z*e2x-e1x*e2z, e3z=e1x*e2y-e1y*e2x;
        sm.rot[0]=e1x; sm.rot[1]=e2x; sm.rot[2]=e3x;
        sm.rot[3]=e1y; sm.rot[4]=e2y; sm.rot[5]=e3y;
        sm.rot[6]=e1z; sm.rot[7]=e2z; sm.rot[8]=e3z;
        sm.ca3[0]=cax; sm.ca3[1]=cay; sm.ca3[2]=caz;
    } else if (tid == 254){
        float c = 0.f;
        for (int s = 0; s < SS; ++s) c += (float)sm.maskb[s];
        sm.cnt = c;
    }
    __syncthreads();
    if (tid < 33){
        int k = tid / 3, i2 = tid - k*3;
        sm.posall3[(A0C + k)*3 + i2] =
            sm.rot[i2*3+0]*sm.pl[k*3+0] + sm.rot[i2*3+1]*sm.pl[k*3+1] +
            sm.rot[i2*3+2]*sm.pl[k*3+2] + sm.ca3[i2];
    }
    __syncthreads();   // posall3 visible to all waves

    // own-row smol coords in REGISTERS
    const float px0 = g_spos[(n*SS + sl0)*3 + 0];
    const float py0 = g_spos[(n*SS + sl0)*3 + 1];
    const float pz0 = g_spos[(n*SS + sl0)*3 + 2];
    const float px1 = g_spos[(n*SS + sl1)*3 + 0];
    const float py1 = g_spos[(n*SS + sl1)*3 + 1];
    const float pz1 = g_spos[(n*SS + sl1)*3 + 2];

    // prefetch slice 0 (wsD k 0..63)
    u32x4 pfa, pfb;
    loadStage(wsD, 256, tid, pfa, pfb);

    // dist for this wave's 32 rows
    #pragma unroll
    for (int aa = 0; aa < 4; ++aa){
        int a = g*4 + aa;
        float ax = sm.posall3[a*3+0], ay = sm.posall3[a*3+1], az = sm.posall3[a*3+2];
        float rx0 = px0-ax, ry0 = py0-ay, rz0 = pz0-az;
        sm.dist[sl0*17 + a] = sqrtf(rx0*rx0 + ry0*ry0 + rz0*rz0 + 1e-6f);
        float rx1 = px1-ax, ry1 = py1-ay, rz1 = pz1-az;
        sm.dist[sl1*17 + a] = sqrtf(rx1*rx1 + ry1*ry1 + rz1*rz1 + 1e-6f);
    }

    const float b0c = (float)((g&1) * 8) * 1.28119724f;
    const float b1a0 = sm.b1v[cB+0*16], b1a1 = sm.b1v[cB+1*16],
                b1a2 = sm.b1v[cB+2*16], b1a3 = sm.b1v[cB+3*16];
    const float b1b0 = sm.b1v[cB+4*16], b1b1 = sm.b1v[cB+5*16],
                b1b2 = sm.b1v[cB+6*16], b1b3 = sm.b1v[cB+7*16];

    // ---- pair GEMM (SWAPPED): accP_m = pair[p=16m+4g+r][s tile0], accQ_m tile1
    f32x4 accP0 = {0.f,0.f,0.f,0.f}, accP1 = accP0, accP2 = accP0, accP3 = accP0;
    f32x4 accQ0 = accP0, accQ1 = accP0, accQ2 = accP0, accQ3 = accP0;

    for (int h = 0; h < 4; ++h){
        pubStage(pfa, pfb, sm.wbuf, tid);
        if (h < 3) loadStage(wsD + (h+1)*64, 256, tid, pfa, pfb);
        else       loadStage(wsDir, 64, tid, pfa, pfb);
        #pragma unroll
        for (int kkl = 0; kkl < 2; ++kkl){
            const int kk = h*2 + kkl;
            bf16x8 av0, av1;
            RBF_FRAG(av0, sl0);
            RBF_FRAG(av1, sl1);
            const unsigned short* bb = &sm.wbuf[cB*72 + kkl*32 + g*8];
            bf16x8 B0 = *(const bf16x8*)(bb +  0*72);
            bf16x8 B1 = *(const bf16x8*)(bb + 16*72);
            bf16x8 B2 = *(const bf16x8*)(bb + 32*72);
            bf16x8 B3 = *(const bf16x8*)(bb + 48*72);
            accP0 = MFMA(B0, av0, accP0);  accQ0 = MFMA(B0, av1, accQ0);
            accP1 = MFMA(B1, av0, accP1);  accQ1 = MFMA(B1, av1, accQ1);
            accP2 = MFMA(B2, av0, accP2);  accQ2 = MFMA(B2, av1, accQ2);
            accP3 = MFMA(B3, av0, accP3);  accQ3 = MFMA(B3, av1, accQ3);
        }
    }

    // ---- + directions @ w_dir ----
    pubStage(pfa, pfb, sm.wbuf, tid);                 // wsDir
    loadStage(wsM1, 64, tid, pfa, pfb);               // prefetch M1a
    #pragma unroll
    for (int kk = 0; kk < 2; ++kk){
        int k0 = kk*32 + g*8;
        unsigned int a0w0 = pk2bf(dirv2(sm,px0,py0,pz0,sl0,k0+0), dirv2(sm,px0,py0,pz0,sl0,k0+1));
        unsigned int a0w1 = pk2bf(dirv2(sm,px0,py0,pz0,sl0,k0+2), dirv2(sm,px0,py0,pz0,sl0,k0+3));
        unsigned int a0w2 = pk2bf(dirv2(sm,px0,py0,pz0,sl0,k0+4), dirv2(sm,px0,py0,pz0,sl0,k0+5));
        unsigned int a0w3 = pk2bf(dirv2(sm,px0,py0,pz0,sl0,k0+6), dirv2(sm,px0,py0,pz0,sl0,k0+7));
        bf16x8 av0 = __builtin_bit_cast(bf16x8, (u32x4){a0w0,a0w1,a0w2,a0w3});
        unsigned int a1w0 = pk2bf(dirv2(sm,px1,py1,pz1,sl1,k0+0), dirv2(sm,px1,py1,pz1,sl1,k0+1));
        unsigned int a1w1 = pk2bf(dirv2(sm,px1,py1,pz1,sl1,k0+2), dirv2(sm,px1,py1,pz1,sl1,k0+3));
        unsigned int a1w2 = pk2bf(dirv2(sm,px1,py1,pz1,sl1,k0+4), dirv2(sm,px1,py1,pz1,sl1,k0+5));
        unsigned int a1w3 = pk2bf(dirv2(sm,px1,py1,pz1,sl1,k0+6), dirv2(sm,px1,py1,pz1,sl1,k0+7));
        bf16x8 av1 = __builtin_bit_cast(bf16x8, (u32x4){a1w0,a1w1,a1w2,a1w3});
        const unsigned short* bb = &sm.wbuf[cB*72 + k0];
        bf16x8 B0 = *(const bf16x8*)(bb +  0*72);
        bf16x8 B1 = *(const bf16x8*)(bb + 16*72);
        bf16x8 B2 = *(const bf16x8*)(bb + 32*72);
        bf16x8 B3 = *(const bf16x8*)(bb + 48*72);
        accP0 = MFMA(B0, av0, accP0);  accQ0 = MFMA(B0, av1, accQ0);
        accP1 = MFMA(B1, av0, accP1);  accQ1 = MFMA(B1, av1, accQ1);
        accP2 = MFMA(B2, av0, accP2);  accQ2 = MFMA(B2, av1, accQ2);
        accP3 = MFMA(B3, av0, accP3);  accQ3 = MFMA(B3, av1, accQ3);
    }

    // ---- epilogue: LN per s-row (lane-local), frags assembled in-register ----
    const int pb  = 4*g;
    const bool hi = (g >> 1);
    const int srcA = ((g&1) << 5) + cB;
    const int srcB = srcA + 16;

    const f32x4 bV0 = *(const f32x4*)&sm.basev[pb +  0];
    const f32x4 bV1 = *(const f32x4*)&sm.basev[pb + 16];
    const f32x4 bV2 = *(const f32x4*)&sm.basev[pb + 32];
    const f32x4 bV3 = *(const f32x4*)&sm.basev[pb + 48];
    const f32x4 sV0 = *(const f32x4*)&sm.lnsc[pb +  0];
    const f32x4 sV1 = *(const f32x4*)&sm.lnsc[pb + 16];
    const f32x4 sV2 = *(const f32x4*)&sm.lnsc[pb + 32];
    const f32x4 sV3 = *(const f32x4*)&sm.lnsc[pb + 48];
    const f32x4 oV0 = *(const f32x4*)&sm.lnof[pb +  0];
    const f32x4 oV1 = *(const f32x4*)&sm.lnof[pb + 16];
    const f32x4 oV2 = *(const f32x4*)&sm.lnof[pb + 32];
    const f32x4 oV3 = *(const f32x4*)&sm.lnof[pb + 48];

    bf16x8 F00, F01, F10, F11;
    {
        f32x4 L0, L1, L2, L3;
        TILE_LN(L0, L1, L2, L3, accP0, accP1, accP2, accP3, ty0);
        MK_FRAG(F00, L0, L1);
        MK_FRAG(F01, L2, L3);
    }
    {
        f32x4 L0, L1, L2, L3;
        TILE_LN(L0, L1, L2, L3, accQ0, accQ1, accQ2, accQ3, ty1);
        MK_FRAG(F10, L0, L1);
        MK_FRAG(F11, L2, L3);
    }

    // ==== MLP1/MLP2 interleaved in k-halves; A-frags from registers ====
    f32x4 accO0 = {0.f,0.f,0.f,0.f}, accO1 = accO0, accO2 = accO0, accO3 = accO0;
    f32x4 accN0 = accO0, accN1 = accO0, accN2 = accO0, accN3 = accO0;

    // ---- MLP1 half a ----
    f32x4 accH0 = {0.f,0.f,0.f,0.f}, accH1 = accH0, accH2 = accH0, accH3 = accH0;
    f32x4 accI0 = accH0, accI1 = accH0, accI2 = accH0, accI3 = accH0;
    pubStage(pfa, pfb, sm.wbuf, tid);                 // M1a; retires dist
    loadStage(wsM2, 128, tid, pfa, pfb);              // prefetch M2a
    #pragma unroll
    for (int kk = 0; kk < 2; ++kk){
        bf16x8 a0 = kk ? F01 : F00;
        bf16x8 a1 = kk ? F11 : F10;
        const unsigned short* bb = &sm.wbuf[cB*72 + kk*32 + g*8];
        bf16x8 B0 = *(const bf16x8*)(bb + 0*16*72);
        bf16x8 B1 = *(const bf16x8*)(bb + 1*16*72);
        bf16x8 B2 = *(const bf16x8*)(bb + 2*16*72);
        bf16x8 B3 = *(const bf16x8*)(bb + 3*16*72);
        accH0 = MFMA(a0, B0, accH0);  accI0 = MFMA(a1, B0, accI0);
        accH1 = MFMA(a0, B1, accH1);  accI1 = MFMA(a1, B1, accI1);
        accH2 = MFMA(a0, B2, accH2);  accI2 = MFMA(a1, B2, accI2);
        accH3 = MFMA(a0, B3, accH3);  accI3 = MFMA(a1, B3, accI3);
    }
    #pragma unroll
    for (int r = 0; r < 4; ++r){
        int slr0 = 32*wv + g*4 + r;
        unsigned short* hr0 = &sm.hidT[slr0*72];
        hr0[cB + 0*16] = f2bfhu(gelu_f(accH0[r] + b1a0));
        hr0[cB + 1*16] = f2bfhu(gelu_f(accH1[r] + b1a1));
        hr0[cB + 2*16] = f2bfhu(gelu_f(accH2[r] + b1a2));
        hr0[cB + 3*16] = f2bfhu(gelu_f(accH3[r] + b1a3));
        unsigned short* hr1 = &sm.hidT[(slr0+16)*72];
        hr1[cB + 0*16] = f2bfhu(gelu_f(accI0[r] + b1a0));
        hr1[cB + 1*16] = f2bfhu(gelu_f(accI1[r] + b1a1));
        hr1[cB + 2*16] = f2bfhu(gelu_f(accI2[r] + b1a2));
        hr1[cB + 3*16] = f2bfhu(gelu_f(accI3[r] + b1a3));
    }

    // ---- MLP2 k-half 0 ----
    pubStage(pfa, pfb, sm.wbuf, tid);                 // M2a; publishes hidT half a
    loadStage(wsM1 + 64*64, 64, tid, pfa, pfb);       // prefetch M1b
    #pragma unroll
    for (int kkl = 0; kkl < 2; ++kkl){
        bf16x8 a0 = *(const bf16x8*)&sm.hidT[sl0*72 + kkl*32 + g*8];
        bf16x8 a1 = *(const bf16x8*)&sm.hidT[sl1*72 + kkl*32 + g*8];
        const unsigned short* bb = &sm.wbuf[cB*72 + kkl*32 + g*8];
        bf16x8 B0 = *(const bf16x8*)(bb + 0*16*72);
        bf16x8 B1 = *(const bf16x8*)(bb + 1*16*72);
        bf16x8 B2 = *(const bf16x8*)(bb + 2*16*72);
        bf16x8 B3 = *(const bf16x8*)(bb + 3*16*72);
        accO0 = MFMA(a0, B0, accO0);  accN0 = MFMA(a1, B0, accN0);
        accO1 = MFMA(a0, B1, accO1);  accN1 = MFMA(a1, B1, accN1);
        accO2 = MFMA(a0, B2, accO2);  accN2 = MFMA(a1, B2, accN2);
        accO3 = MFMA(a0, B3, accO3);  accN3 = MFMA(a1, B3, accN3);
    }

    // ---- MLP1 half b (reusing the SAME frags) ----
    f32x4 accH4 = {0.f,0.f,0.f,0.f}, accH5 = accH4, accH6 = accH4, accH7 = accH4;
    f32x4 accI4 = accH4, accI5 = accH4, accI6 = accH4, accI7 = accH4;
    pubStage(pfa, pfb, sm.wbuf, tid);                 // M1b; retires hidT-half-a reads
    loadStage(wsM2 + 64, 128, tid, pfa, pfb);         // prefetch M2b
    #pragma unroll
    for (int kk = 0; kk < 2; ++kk){
        bf16x8 a0 = kk ? F01 : F00;
        bf16x8 a1 = kk ? F11 : F10;
        const unsigned short* bb = &sm.wbuf[cB*72 + kk*32 + g*8];
        bf16x8 B0 = *(const bf16x8*)(bb + 0*16*72);
        bf16x8 B1 = *(const bf16x8*)(bb + 1*16*72);
        bf16x8 B2 = *(const bf16x8*)(bb + 2*16*72);
        bf16x8 B3 = *(const bf16x8*)(bb + 3*16*72);
        accH4 = MFMA(a0, B0, accH4);  accI4 = MFMA(a1, B0, accI4);
        accH5 = MFMA(a0, B1, accH5);  accI5 = MFMA(a1, B1, accI5);
        accH6 = MFMA(a0, B2, accH6);  accI6 = MFMA(a1, B2, accI6);
        accH7 = MFMA(a0, B3, accH7);  accI7 = MFMA(a1, B3, accI7);
    }
    #pragma unroll
    for (int r = 0; r < 4; ++r){
        int slr0 = 32*wv + g*4 + r;
        unsigned short* hr0 = &sm.hidT[slr0*72];
        hr0[cB + 0*16] = f2bfhu(gelu_f(accH4[r] + b1b0));
        hr0[cB + 1*16] = f2bfhu(gelu_f(accH5[r] + b1b1));
        hr0[cB + 2*16] = f2bfhu(gelu_f(accH6[r] + b1b2));
        hr0[cB + 3*16] = f2bfhu(gelu_f(accH7[r] + b1b3));
        unsigned short* hr1 = &sm.hidT[(slr0+16)*72];
        hr1[cB + 0*16] = f2bfhu(gelu_f(accI4[r] + b1b0));
        hr1[cB + 1*16] = f2bfhu(gelu_f(accI5[r] + b1b1));
        hr1[cB + 2*16] = f2bfhu(gelu_f(accI6[r] + b1b2));
        hr1[cB + 3*16] = f2bfhu(gelu_f(accI7[r] + b1b3));
    }

    // ---- MLP2 k-half 1 ----
    pubStage(pfa, pfb, sm.wbuf, tid);                 // M2b; publishes hidT half b
    #pragma unroll
    for (int kkl = 0; kkl < 2; ++kkl){
        bf16x8 a0 = *(const bf16x8*)&sm.hidT[sl0*72 + kkl*32 + g*8];
        bf16x8 a1 = *(const bf16x8*)&sm.hidT[sl1*72 + kkl*32 + g*8];
        const unsigned short* bb = &sm.wbuf[cB*72 + kkl*32 + g*8];
        bf16x8 B0 = *(const bf16x8*)(bb + 0*16*72);
        bf16x8 B1 = *(const bf16x8*)(bb + 1*16*72);
        bf16x8 B2 = *(const bf16x8*)(bb + 2*16*72);
        bf16x8 B3 = *(const bf16x8*)(bb + 3*16*72);
        accO0 = MFMA(a0, B0, accO0);  accN0 = MFMA(a1, B0, accN0);
        accO1 = MFMA(a0, B1, accO1);  accN1 = MFMA(a1, B1, accN1);
        accO2 = MFMA(a0, B2, accO2);  accN2 = MFMA(a1, B2, accN2);
        accO3 = MFMA(a0, B3, accO3);  accN3 = MFMA(a1, B3, accN3);
    }

    float pooled0 = 0.f, pooled1 = 0.f, pooled2 = 0.f, pooled3 = 0.f;
    #pragma unroll
    for (int r = 0; r < 4; ++r){
        float m0f = sm.maskb[32*wv + g*4 + r]      ? 1.0f : 0.0f;
        float m1f = sm.maskb[32*wv + 16 + g*4 + r] ? 1.0f : 0.0f;
        pooled0 += m0f * accO0[r] + m1f * accN0[r];
        pooled1 += m0f * accO1[r] + m1f * accN1[r];
        pooled2 += m0f * accO2[r] + m1f * accN2[r];
        pooled3 += m0f * accO3[r] + m1f * accN3[r];
    }

    // ---- reduce pooled: across g-groups, then across waves ----
    pooled0 += __shfl_xor(pooled0,16); pooled0 += __shfl_xor(pooled0,32);
    pooled1 += __shfl_xor(pooled1,16); pooled1 += __shfl_xor(pooled1,32);
    pooled2 += __shfl_xor(pooled2,16); pooled2 += __shfl_xor(pooled2,32);
    pooled3 += __shfl_xor(pooled3,16); pooled3 += __shfl_xor(pooled3,32);
    if (g == 0){
        sm.rf.red[wv*PD + cB +  0] = pooled0;
        sm.rf.red[wv*PD + cB + 16] = pooled1;
        sm.rf.red[wv*PD + cB + 32] = pooled2;
        sm.rf.red[wv*PD + cB + 48] = pooled3;
    }
    __syncthreads();
    if (tid < PD){
        float v = sm.rf.red[tid] + sm.rf.red[PD + tid] + sm.rf.red[2*PD + tid] + sm.rf.red[3*PD + tid];
        float mc = fmaxf(sm.cnt, 1.0f);
        v = (v + sm.cnt * sm.b2v[tid]) / mc;
        sm.rf.fin[tid] = sm.gatevv[tid] * v;
    }
    __syncthreads();
    {
        float a = 0.f;
        #pragma unroll 4
        for (int p = 0; p < PD; ++p) a += sm.rf.fin[p] * w_out[p*LD + tid];
        g_out[n*LD + tid] = a;
    }
}

extern "C" void kernel_launch(void* const* d_in, const int* in_sizes, int n_in,
                              void* d_out, int out_size, void* d_ws, size_t ws_size,
                              hipStream_t stream)
{
    (void)in_sizes; (void)n_in; (void)out_size; (void)ws_size;
    const float* g_local   = (const float*)d_in[0];
    const float* g_pos     = (const float*)d_in[1];
    const int*   g_type    = (const int*)  d_in[2];
    const float* g_spos    = (const float*)d_in[3];
    const int*   g_mask    = (const int*)  d_in[4];
    const float* w_points  = (const float*)d_in[5];
    const float* w_type    = (const float*)d_in[6];
    const float* w_local   = (const float*)d_in[7];
    const float* w_dir     = (const float*)d_in[8];
    const float* w_dist    = (const float*)d_in[9];
    const float* ln_scale  = (const float*)d_in[10];
    const float* ln_offset = (const float*)d_in[11];
    const float* w_mlp1    = (const float*)d_in[12];
    const float* b_mlp1    = (const float*)d_in[13];
    const float* w_mlp2    = (const float*)d_in[14];
    const float* b_mlp2    = (const float*)d_in[15];
    const float* w_gate    = (const float*)d_in[16];
    const float* w_out     = (const float*)d_in[17];

    unsigned short* ws = (unsigned short*)d_ws;   // 73728 B

    smol_prep<<<dim3(144), dim3(256), 0, stream>>>(w_dist, w_dir, w_mlp1, w_mlp2, ws);

    smol_fused<<<dim3(NRES), dim3(256), 0, stream>>>(
        g_local, g_pos, g_type, g_spos, g_mask,
        w_points, w_local, w_type, ln_scale, ln_offset,
        b_mlp1, b_mlp2, w_gate, w_out, ws, (float*)d_out);
}